// Round 2
// baseline (80.420 us; speedup 1.0000x reference)
//
#include <hip/hip_runtime.h>

constexpr int NB = 32;    // batch
constexpr int NS = 4096;  // sequence
constexpr int ND = 512;   // feature dim

// e = exp(tanh(s)) without libm tanhf:
//   t = e^{2s};  tanh(s) = (t-1)/(t+1);  two v_exp_f32 + one v_rcp_f32.
// s clamped to +-15 so t stays finite (tanh(15)==1 in fp32 anyway).
__device__ __forceinline__ float exp_tanh(float s) {
    s = fminf(fmaxf(s, -15.f), 15.f);
    float t  = __expf(2.0f * s);
    float th = (t - 1.0f) * __builtin_amdgcn_rcpf(t + 1.0f);
    return __expf(th);
}

__device__ __forceinline__ float dot8(const float4& a1, const float4& a2,
                                      const float4& w1, const float4& w2) {
    return a1.x * w1.x + a1.y * w1.y + a1.z * w1.z + a1.w * w1.w
         + a2.x * w2.x + a2.y * w2.y + a2.z * w2.z + a2.w * w2.w;
}

// ---------------------------------------------------------------------------
// Pass 1: one streaming pass over x.
// Grid: (nchunk, NB) x 256 threads (4 waves). Each wave owns chunk/4
// consecutive rows and processes 4 rows per iteration: 8 dwordx4 loads in
// flight per wave (8 KB) before any dependent use -> latency hiding.
// Per row: wave-64 dot with W (register-resident), shuffle reduce,
// e = exp(tanh(dot+bias)) (tanh bounds scores -> softmax needs no max),
// e stored unnormalized to the weights output, context partial accumulated
// in registers. Block epilogue combines 4 waves via LDS -> per-chunk (Z, c).
// ---------------------------------------------------------------------------
__global__ __launch_bounds__(256) void attn_pass1(
    const float* __restrict__ x, const float* __restrict__ W,
    const float* __restrict__ bias,
    float* __restrict__ e_out,   // [NB*NS]   (weights region of d_out)
    float* __restrict__ Zp,      // [NB*nchunk]
    float* __restrict__ Cp,      // [NB*nchunk*ND]
    int nchunk, int chunk)
{
    const int b    = blockIdx.y;
    const int ch   = blockIdx.x;
    const int tid  = threadIdx.x;
    const int wv   = tid >> 6;      // 0..3
    const int lane = tid & 63;

    const float4 w1 = *(const float4*)(W + 4 * lane);
    const float4 w2 = *(const float4*)(W + 256 + 4 * lane);

    const float* xb = x + (size_t)b * NS * ND;
    const int rpw  = chunk >> 2;            // rows per wave (multiple of 4)
    const int row0 = ch * chunk + wv * rpw;

    float4 c1 = make_float4(0.f, 0.f, 0.f, 0.f);
    float4 c2 = make_float4(0.f, 0.f, 0.f, 0.f);
    float zacc = 0.f;

    for (int r = 0; r < rpw; r += 4) {
        const int i0 = row0 + r;
        const float* p = xb + (size_t)i0 * ND + 4 * lane;
        // 4 consecutive rows, 2 float4 each (d = 4*lane and 256+4*lane)
        float4 a1 = *(const float4*)(p);
        float4 a2 = *(const float4*)(p + 256);
        float4 b1 = *(const float4*)(p + 512);
        float4 b2 = *(const float4*)(p + 768);
        float4 d1 = *(const float4*)(p + 1024);
        float4 d2 = *(const float4*)(p + 1280);
        float4 e1 = *(const float4*)(p + 1536);
        float4 e2 = *(const float4*)(p + 1792);

        float p0 = dot8(a1, a2, w1, w2);
        float p1 = dot8(b1, b2, w1, w2);
        float p2 = dot8(d1, d2, w1, w2);
        float p3 = dot8(e1, e2, w1, w2);
        #pragma unroll
        for (int m = 32; m >= 1; m >>= 1) {
            p0 += __shfl_xor(p0, m);
            p1 += __shfl_xor(p1, m);
            p2 += __shfl_xor(p2, m);
            p3 += __shfl_xor(p3, m);
        }
        const float4 bb = *(const float4*)(bias + i0);
        float q0 = exp_tanh(p0 + bb.x);
        float q1 = exp_tanh(p1 + bb.y);
        float q2 = exp_tanh(p2 + bb.z);
        float q3 = exp_tanh(p3 + bb.w);
        if (lane == 0)
            *(float4*)(e_out + (size_t)b * NS + i0) = make_float4(q0, q1, q2, q3);
        zacc += (q0 + q1) + (q2 + q3);

        c1.x += a1.x * q0 + b1.x * q1 + d1.x * q2 + e1.x * q3;
        c1.y += a1.y * q0 + b1.y * q1 + d1.y * q2 + e1.y * q3;
        c1.z += a1.z * q0 + b1.z * q1 + d1.z * q2 + e1.z * q3;
        c1.w += a1.w * q0 + b1.w * q1 + d1.w * q2 + e1.w * q3;
        c2.x += a2.x * q0 + b2.x * q1 + d2.x * q2 + e2.x * q3;
        c2.y += a2.y * q0 + b2.y * q1 + d2.y * q2 + e2.y * q3;
        c2.z += a2.z * q0 + b2.z * q1 + d2.z * q2 + e2.z * q3;
        c2.w += a2.w * q0 + b2.w * q1 + d2.w * q2 + e2.w * q3;
    }

    // Combine the 4 waves through LDS.
    __shared__ __align__(16) float lc[4][ND];
    __shared__ float lz[4];
    *(float4*)&lc[wv][4 * lane]       = c1;
    *(float4*)&lc[wv][256 + 4 * lane] = c2;
    if (lane == 0) lz[wv] = zacc;
    __syncthreads();

    float* cp = Cp + ((size_t)b * nchunk + ch) * ND;
    for (int d = tid; d < ND; d += 256)
        cp[d] = lc[0][d] + lc[1][d] + lc[2][d] + lc[3][d];
    if (tid == 0)
        Zp[b * nchunk + ch] = lz[0] + lz[1] + lz[2] + lz[3];
}

// ---------------------------------------------------------------------------
// Pass 2: per-batch finalize. Grid: NB blocks of 256 threads.
// ---------------------------------------------------------------------------
__global__ __launch_bounds__(256) void attn_pass2(
    const float* __restrict__ Zp, const float* __restrict__ Cp,
    float* __restrict__ w_inout,   // [NB*NS]
    float* __restrict__ ctx,       // [NB*ND]
    int nchunk)
{
    const int b = blockIdx.x;
    __shared__ float zs;

    if (threadIdx.x < 64) {
        float z = (threadIdx.x < nchunk) ? Zp[b * nchunk + threadIdx.x] : 0.f;
        #pragma unroll
        for (int m = 32; m >= 1; m >>= 1) z += __shfl_xor(z, m);
        if (threadIdx.x == 0) zs = z;
    }
    __syncthreads();
    const float invZ = 1.0f / zs;

    const float* cpb = Cp + (size_t)b * nchunk * ND;
    for (int d = threadIdx.x; d < ND; d += 256) {
        float v = 0.f;
        for (int c = 0; c < nchunk; ++c) v += cpb[(size_t)c * ND + d];
        ctx[b * ND + d] = v * invZ;
    }
    float* wb = w_inout + (size_t)b * NS;
    for (int i = threadIdx.x; i < NS; i += 256)
        wb[i] *= invZ;
}

extern "C" void kernel_launch(void* const* d_in, const int* in_sizes, int n_in,
                              void* d_out, int out_size, void* d_ws, size_t ws_size,
                              hipStream_t stream) {
    const float* x    = (const float*)d_in[0];
    const float* W    = (const float*)d_in[1];
    const float* bias = (const float*)d_in[2];

    float* ctx = (float*)d_out;            // [NB*ND]
    float* wts = ctx + NB * ND;            // [NB*NS]

    // Largest chunk count whose partials fit the workspace (and <=64 so the
    // pass-2 wave reduce covers it).
    int nchunk = 64;
    while (nchunk > 1 &&
           (size_t)4 * NB * nchunk * (1 + ND) > ws_size)
        nchunk >>= 1;
    const int chunk = NS / nchunk;         // multiple of 16

    float* Zp = (float*)d_ws;
    float* Cp = Zp + (size_t)NB * nchunk;

    hipLaunchKernelGGL(attn_pass1, dim3(nchunk, NB), dim3(256), 0, stream,
                       x, W, bias, wts, Zp, Cp, nchunk, chunk);
    hipLaunchKernelGGL(attn_pass2, dim3(NB), dim3(256), 0, stream,
                       Zp, Cp, wts, ctx, nchunk);
}

// Round 3
// 51.462 us; speedup vs baseline: 1.5627x; 1.5627x over previous
//
#include <hip/hip_runtime.h>

constexpr int NB = 32;    // batch
constexpr int NS = 4096;  // sequence
constexpr int ND = 512;   // feature dim

// e = exp(tanh(s)) without libm tanhf:
//   t = e^{2s};  tanh(s) = (t-1)/(t+1);  two v_exp_f32 + one v_rcp_f32.
// s clamped to +-15 so t stays finite (tanh(15)==1 in fp32 anyway).
__device__ __forceinline__ float exp_tanh(float s) {
    s = fminf(fmaxf(s, -15.f), 15.f);
    float t  = __expf(2.0f * s);
    float th = (t - 1.0f) * __builtin_amdgcn_rcpf(t + 1.0f);
    return __expf(th);
}

// ---------------------------------------------------------------------------
// Pass 1: one streaming pass over x.  (R1 structure: interleaved 2-row wave
// pattern — block's 4 waves cover 8 consecutive rows per step, compact
// sliding window.)  Per row: wave-64 dot with register-resident W, shuffle
// reduce, e = exp(tanh(dot+bias)) (tanh bounds scores -> no softmax max),
// e stored unnormalized into the weights output, context partial accumulated
// in registers.  Epilogue: 4-wave LDS combine -> per-chunk (Z, c[512]).
// ---------------------------------------------------------------------------
__global__ __launch_bounds__(256) void attn_pass1(
    const float* __restrict__ x, const float* __restrict__ W,
    const float* __restrict__ bias,
    float* __restrict__ e_out,   // [NB*NS]   (weights region of d_out)
    float* __restrict__ Zp,      // [NB*nchunk]
    float* __restrict__ Cp,      // [NB*nchunk*ND]
    int nchunk, int chunk)
{
    const int b    = blockIdx.y;
    const int ch   = blockIdx.x;
    const int tid  = threadIdx.x;
    const int wv   = tid >> 6;      // 0..3
    const int lane = tid & 63;

    const float4 w1 = *(const float4*)(W + 4 * lane);
    const float4 w2 = *(const float4*)(W + 256 + 4 * lane);

    const float* xb = x + (size_t)b * NS * ND;
    const int row0 = ch * chunk;

    float4 c1 = make_float4(0.f, 0.f, 0.f, 0.f);
    float4 c2 = make_float4(0.f, 0.f, 0.f, 0.f);
    float zacc = 0.f;

    // chunk is a multiple of 8; waves 0..3 each process pairs (r, r+4).
    for (int r = wv; r < chunk; r += 8) {
        const int ia = row0 + r;
        const int ib = ia + 4;
        const float* xra = xb + (size_t)ia * ND;
        const float* xrb = xb + (size_t)ib * ND;
        float4 a1 = *(const float4*)(xra + 4 * lane);
        float4 a2 = *(const float4*)(xra + 256 + 4 * lane);
        float4 b1 = *(const float4*)(xrb + 4 * lane);
        float4 b2 = *(const float4*)(xrb + 256 + 4 * lane);

        float pa = a1.x * w1.x + a1.y * w1.y + a1.z * w1.z + a1.w * w1.w
                 + a2.x * w2.x + a2.y * w2.y + a2.z * w2.z + a2.w * w2.w;
        float pb = b1.x * w1.x + b1.y * w1.y + b1.z * w1.z + b1.w * w1.w
                 + b2.x * w2.x + b2.y * w2.y + b2.z * w2.z + b2.w * w2.w;
        #pragma unroll
        for (int m = 32; m >= 1; m >>= 1) {
            pa += __shfl_xor(pa, m);
            pb += __shfl_xor(pb, m);
        }
        float ea = exp_tanh(pa + bias[ia]);
        float eb = exp_tanh(pb + bias[ib]);
        if (lane == 0) {
            e_out[(size_t)b * NS + ia] = ea;
            e_out[(size_t)b * NS + ib] = eb;
        }
        zacc += ea + eb;
        c1.x += a1.x * ea + b1.x * eb;
        c1.y += a1.y * ea + b1.y * eb;
        c1.z += a1.z * ea + b1.z * eb;
        c1.w += a1.w * ea + b1.w * eb;
        c2.x += a2.x * ea + b2.x * eb;
        c2.y += a2.y * ea + b2.y * eb;
        c2.z += a2.z * ea + b2.z * eb;
        c2.w += a2.w * ea + b2.w * eb;
    }

    // Combine the 4 waves through LDS.
    __shared__ __align__(16) float lc[4][ND];
    __shared__ float lz[4];
    *(float4*)&lc[wv][4 * lane]       = c1;
    *(float4*)&lc[wv][256 + 4 * lane] = c2;
    if (lane == 0) lz[wv] = zacc;
    __syncthreads();

    float* cp = Cp + ((size_t)b * nchunk + ch) * ND;
    for (int d = tid; d < ND; d += 256)
        cp[d] = lc[0][d] + lc[1][d] + lc[2][d] + lc[3][d];
    if (tid == 0)
        Zp[b * nchunk + ch] = lz[0] + lz[1] + lz[2] + lz[3];
}

// ---------------------------------------------------------------------------
// Pass 2: finalize.  Grid: (NB, 8) x 256 threads — 256 blocks so the whole
// machine participates (the old 32-block version was latency-bound on 1/8th
// of the chip).  Every block redundantly computes Z for its batch (cheap),
// then block (b, j) writes context dims [j*64, j*64+64) and rescales weights
// [j*512, j*512+512).
// ---------------------------------------------------------------------------
__global__ __launch_bounds__(256) void attn_pass2(
    const float* __restrict__ Zp, const float* __restrict__ Cp,
    float* __restrict__ w_inout,   // [NB*NS]
    float* __restrict__ ctx,       // [NB*ND]
    int nchunk)
{
    const int b = blockIdx.x;
    const int j = blockIdx.y;
    const int t = threadIdx.x;

    __shared__ float zs;
    __shared__ float lc[4][64];

    if (t < 64) {
        float z = (t < nchunk) ? Zp[b * nchunk + t] : 0.f;
        #pragma unroll
        for (int m = 32; m >= 1; m >>= 1) z += __shfl_xor(z, m);
        if (t == 0) zs = z;
    }
    __syncthreads();
    const float invZ = 1.0f / zs;

    // context slice: 4 chunk-groups x 64 dims, coalesced over d.
    const int cg = t >> 6;          // 0..3
    const int dl = t & 63;
    const int d  = j * 64 + dl;
    const float* cpb = Cp + (size_t)b * nchunk * ND;
    float v = 0.f;
    for (int c = cg; c < nchunk; c += 4)
        v += cpb[(size_t)c * ND + d];
    lc[cg][dl] = v;
    __syncthreads();
    if (t < 64)
        ctx[b * ND + j * 64 + t] = (lc[0][t] + lc[1][t] + lc[2][t] + lc[3][t]) * invZ;

    // weights slice: 512 elements as float2 per thread.
    float2* wb = (float2*)(w_inout + (size_t)b * NS + j * 512);
    float2 w = wb[t];
    w.x *= invZ; w.y *= invZ;
    wb[t] = w;
}

extern "C" void kernel_launch(void* const* d_in, const int* in_sizes, int n_in,
                              void* d_out, int out_size, void* d_ws, size_t ws_size,
                              hipStream_t stream) {
    const float* x    = (const float*)d_in[0];
    const float* W    = (const float*)d_in[1];
    const float* bias = (const float*)d_in[2];

    float* ctx = (float*)d_out;            // [NB*ND]
    float* wts = ctx + NB * ND;            // [NB*NS]

    // Largest chunk count whose partials fit the workspace (<=64 so the
    // pass-2 wave reduce covers it).
    int nchunk = 64;
    while (nchunk > 1 &&
           (size_t)4 * NB * nchunk * (1 + ND) > ws_size)
        nchunk >>= 1;
    const int chunk = NS / nchunk;         // multiple of 8

    float* Zp = (float*)d_ws;
    float* Cp = Zp + (size_t)NB * nchunk;

    hipLaunchKernelGGL(attn_pass1, dim3(nchunk, NB), dim3(256), 0, stream,
                       x, W, bias, wts, Zp, Cp, nchunk, chunk);
    hipLaunchKernelGGL(attn_pass2, dim3(NB, 8), dim3(256), 0, stream,
                       Zp, Cp, wts, ctx, nchunk);
}